// Round 3
// baseline (360.795 us; speedup 1.0000x reference)
//
#include <hip/hip_runtime.h>
#include <hip/hip_bf16.h>
#include <stdint.h>

// Problem constants
#define B_   16
#define H_   112
#define W_   112
#define CIN  128
#define F_   256
#define OH   110
#define OW   110
#define TPI  (OH*OW)           // 12100 output pixels per image
#define MTOT (B_*TPI)          // 193600
#define KTOT 1152
#define PIX_IN (B_*H_*W_)      // 200704
#define D_INV (1.0f/1152.0f)
#define TILES_PER_IMG 95       // ceil(12100/128)
#define WSTR 136               // padded window pixel stride (128 + 8)
#define WIN_BYTES (5*112*WSTR) // 76160

typedef int intx4 __attribute__((ext_vector_type(4)));

// ws layout (bytes):
//   wst  i8   [18 ks][2 fh][4 chunk][128 n][16 j]  = 294912
//   sf   f32  [256]
//   S    f32  [PIX_IN]
//   beta f32  [MTOT]
//   xq   i8   [PIX_IN*CIN]
#define WST_OFF   0
#define SF_OFF    294912
#define S_OFF     295936
#define BETA_OFF  1098752
#define XQ_OFF    1873152
#define NEED_FULL (XQ_OFF + (size_t)PIX_IN*CIN)

// ---- prep: W' = sum_e alpha[e,f]*sign(K_e); quantize i8 with s_f ----------
__global__ void prep_wq(const float* __restrict__ kern, const float* __restrict__ alph,
                        int8_t* __restrict__ wst, float* __restrict__ sf) {
    int idx = blockIdx.x * 256 + threadIdx.x;   // = r*256 + f
    int r = idx >> 8, f = idx & 255;
    float a0 = alph[f], a1 = alph[256 + f], a2 = alph[512 + f];  // >= 0
    float w = 0.f;
    float kv0 = kern[idx], kv1 = kern[294912 + idx], kv2 = kern[589824 + idx];
    w += (__float_as_uint(kv0) & 0x80000000u) ? -a0 : a0;
    w += (__float_as_uint(kv1) & 0x80000000u) ? -a1 : a1;
    w += (__float_as_uint(kv2) & 0x80000000u) ? -a2 : a2;
    float s = (a0 + a1 + a2) * (1.0f / 127.0f);          // bounds |w| -> |q|<=127
    int q = (int)__builtin_rintf(w / s);
    // image addr: [ks=r>>6][fh=f>>7][chunk=(r>>4)&3][n=f&127][j=r&15]
    wst[((((r >> 6) * 2 + (f >> 7)) * 4 + ((r >> 4) & 3)) * 128 + (f & 127)) * 16 + (r & 15)]
        = (int8_t)q;
    if (r == 0) sf[f] = s;
}

// ---- prep: binarize x -> xq (i8 +-1), per-pixel sum|x| --------------------
__device__ __forceinline__ uint32_t pack4sign(float4 v) {
    uint32_t b0 = ((__float_as_uint(v.x) >> 31) * 0xFEu) ^ 0x01u;
    uint32_t b1 = ((__float_as_uint(v.y) >> 31) * 0xFEu) ^ 0x01u;
    uint32_t b2 = ((__float_as_uint(v.z) >> 31) * 0xFEu) ^ 0x01u;
    uint32_t b3 = ((__float_as_uint(v.w) >> 31) * 0xFEu) ^ 0x01u;
    return b0 | (b1 << 8) | (b2 << 16) | (b3 << 24);
}

__global__ void prep_x(const float* __restrict__ x, uint32_t* __restrict__ xq,
                       float* __restrict__ S, int write_xq) {
    int idx = blockIdx.x * 256 + threadIdx.x;   // float4 index; 32 per pixel
    float4 v = ((const float4*)x)[idx];
    if (write_xq) xq[idx] = pack4sign(v);
    float s = fabsf(v.x) + fabsf(v.y) + fabsf(v.z) + fabsf(v.w);
#pragma unroll
    for (int o = 1; o < 32; o <<= 1) s += __shfl_xor(s, o, 64);
    if ((threadIdx.x & 31) == 0) S[idx >> 5] = s;
}

// ---- prep: beta = 3x3 box of S / 1152 -------------------------------------
__global__ void prep_beta(const float* __restrict__ S, float* __restrict__ beta) {
    int m = blockIdx.x * 256 + threadIdx.x;
    if (m >= MTOT) return;
    int b = m / TPI; int r = m - b * TPI;
    int oi = r / OW, oj = r - oi * OW;
    const float* sp = S + (b * H_ + oi) * W_ + oj;
    float acc = 0.f;
#pragma unroll
    for (int dh = 0; dh < 3; ++dh)
#pragma unroll
        for (int dw = 0; dw < 3; ++dw) acc += sp[dh * W_ + dw];
    beta[m] = acc * D_INV;
}

// ---- main: zero-barrier K-loop. A resident in LDS window, B global->VGPR --
template <bool PREBIN>
__global__ __launch_bounds__(256, 2)
void conv_main(const void* __restrict__ xin, const int8_t* __restrict__ wst,
               const float* __restrict__ sf, const float* __restrict__ beta,
               float* __restrict__ out) {
    __shared__ char smem[WIN_BYTES];   // [5 pixrow][112 pixcol] stride 136, 128 ch

    const int t = threadIdx.x;
    const int l = t & 63, wv = t >> 6;
    const int quad = l >> 4, lane16 = l & 15;
    const int wm = wv >> 1, wn = wv & 1;
    const int f0 = blockIdx.x * 128;
    const int img = blockIdx.y / TILES_PER_IMG;
    const int tile = blockIdx.y - img * TILES_PER_IMG;
    const int p0 = tile * 128;          // first output pixel (within image)
    const int oi0 = p0 / OW;            // first input row of window

    // ---- stage A window (once) ----
    if (PREBIN) {
        const char* xi = (const char*)xin + (size_t)img * (H_ * W_ * CIN);
        for (int i = t; i < 4480; i += 256) {       // 560 pixels * 8 chunks
            int pix = i >> 3, chunk = i & 7;
            int wr = pix / 112, wc = pix - wr * 112;
            int gr = oi0 + wr; if (gr > 111) gr = 111;
            uint4 v = *(const uint4*)(xi + ((gr * W_ + wc) * CIN + chunk * 16));
            *(uint4*)(smem + pix * WSTR + chunk * 16) = v;
        }
    } else {
        const float* xi = (const float*)xin + (size_t)img * (H_ * W_ * CIN);
        for (int i = t; i < 4480; i += 256) {
            int pix = i >> 3, chunk = i & 7;
            int wr = pix / 112, wc = pix - wr * 112;
            int gr = oi0 + wr; if (gr > 111) gr = 111;
            const float4* s = (const float4*)(xi + (gr * W_ + wc) * CIN + chunk * 16);
            uint4 pv = make_uint4(pack4sign(s[0]), pack4sign(s[1]),
                                  pack4sign(s[2]), pack4sign(s[3]));
            *(uint4*)(smem + pix * WSTR + chunk * 16) = pv;
        }
    }

    // per-lane A base addresses (window-relative), one per m-fragment
    int abase[4];
#pragma unroll
    for (int tm = 0; tm < 4; ++tm) {
        int p = p0 + wm * 64 + tm * 16 + lane16;
        if (p > TPI - 1) p = TPI - 1;
        int oi = p / OW, oj = p - oi * OW;
        abase[tm] = ((oi - oi0) * 112 + oj) * WSTR + quad * 16;
    }

    // B fragment global base: wst + fh*8192 + ks*16384 + quad*2048 + col*16
    const char* bbase = (const char*)wst + blockIdx.x * 8192 + quad * 2048
                        + (wn * 64 + lane16) * 16;

    __syncthreads();   // the only barrier in this kernel

    intx4 acc[4][4];
#pragma unroll
    for (int a = 0; a < 4; ++a)
#pragma unroll
        for (int bb = 0; bb < 4; ++bb) acc[a][bb] = (intx4){0, 0, 0, 0};

    // depth-2 B prefetch, 3-buffer rotation
    intx4 b0[4], b1[4], b2[4];
#pragma unroll
    for (int tn = 0; tn < 4; ++tn) {
        b0[tn] = *(const intx4*)(bbase + tn * 256);
        b1[tn] = *(const intx4*)(bbase + 16384 + tn * 256);
    }

    auto step = [&](int ks, intx4 (&bc)[4], intx4 (&bp)[4]) {
        int ksp = ks + 2; if (ksp > 17) ksp = 0;   // harmless dup prefetch at tail
#pragma unroll
        for (int tn = 0; tn < 4; ++tn)
            bp[tn] = *(const intx4*)(bbase + ksp * 16384 + tn * 256);
        int kh = (ks * 171) >> 10;                  // ks/6 for ks<18
        int rem = ks - kh * 6;
        int aoff = (kh * 112 + (rem >> 1)) * WSTR + (rem & 1) * 64;
        intx4 af[4];
#pragma unroll
        for (int tm = 0; tm < 4; ++tm)
            af[tm] = *(const intx4*)(smem + abase[tm] + aoff);
#pragma unroll
        for (int tm = 0; tm < 4; ++tm)
#pragma unroll
            for (int tn = 0; tn < 4; ++tn)
                acc[tm][tn] = __builtin_amdgcn_mfma_i32_16x16x64_i8(
                    af[tm], bc[tn], acc[tm][tn], 0, 0, 0);
    };

    for (int kb = 0; kb < 18; kb += 3) {
        step(kb + 0, b0, b2);
        step(kb + 1, b1, b0);
        step(kb + 2, b2, b1);
    }

    // epilogue: out[m,f] = beta[m] * sf[f] * acc
    float sv[4];
#pragma unroll
    for (int tn = 0; tn < 4; ++tn) sv[tn] = sf[f0 + wn * 64 + tn * 16 + lane16];

    const size_t mbase = (size_t)img * TPI;
#pragma unroll
    for (int tm = 0; tm < 4; ++tm) {
#pragma unroll
        for (int i = 0; i < 4; ++i) {
            int p = p0 + wm * 64 + tm * 16 + quad * 4 + i;
            if (p < TPI) {
                size_t m = mbase + p;
                float bv = beta[m];
                float* op = out + m * F_ + f0 + wn * 64 + lane16;
#pragma unroll
                for (int tn = 0; tn < 4; ++tn)
                    op[tn * 16] = (float)acc[tm][tn][i] * (bv * sv[tn]);
            }
        }
    }
}

extern "C" void kernel_launch(void* const* d_in, const int* in_sizes, int n_in,
                              void* d_out, int out_size, void* d_ws, size_t ws_size,
                              hipStream_t stream) {
    const float* x    = (const float*)d_in[0];
    const float* kern = (const float*)d_in[1];
    const float* alph = (const float*)d_in[2];
    float* out = (float*)d_out;
    char* ws = (char*)d_ws;

    int8_t* wst  = (int8_t*)(ws + WST_OFF);
    float*  sf   = (float*)(ws + SF_OFF);
    float*  S    = (float*)(ws + S_OFF);
    float*  beta = (float*)(ws + BETA_OFF);
    char*   xq   = ws + XQ_OFF;
    bool prebin = ws_size >= NEED_FULL;

    hipLaunchKernelGGL(prep_wq, dim3(KTOT * F_ / 256), dim3(256), 0, stream,
                       kern, alph, wst, sf);
    hipLaunchKernelGGL(prep_x, dim3(PIX_IN * CIN / 4 / 256), dim3(256), 0, stream,
                       x, (uint32_t*)xq, S, (int)prebin);
    hipLaunchKernelGGL(prep_beta, dim3((MTOT + 255) / 256), dim3(256), 0, stream, S, beta);

    dim3 grid(2, B_ * TILES_PER_IMG);   // f-halves x per-image m-tiles
    if (prebin)
        hipLaunchKernelGGL(conv_main<true>, grid, dim3(256), 0, stream,
                           (const void*)xq, wst, sf, beta, out);
    else
        hipLaunchKernelGGL(conv_main<false>, grid, dim3(256), 0, stream,
                           (const void*)x, wst, sf, beta, out);
}